// Round 1
// baseline (246.351 us; speedup 1.0000x reference)
//
#include <hip/hip_runtime.h>

// ---------------------------------------------------------------------------
// sLSTM cell, B=8192, D=1024, H=1024.
//   pre[B,4H] = [x,h_prev] @ [Wg|Rg]^T  (K = D+H = 2048), gates packed i,f,o,z
//   epilogue: i=exp(pi+bi), f=sig(pf+bf), o=sig(po+bo), z=tanh(pz+bz)
//             c=f*c_prev+i*z ; n=f*n_prev+i ; m=max(log f + m_prev, pi) ; h=o*c/n
//   outputs (flat, concat): h, c, C_prev(copy), n, m  -- each B*H f32
// GEMM in fp16 MFMA (same rate as bf16, 8x mantissa) accum f32.
// ---------------------------------------------------------------------------

#define B_SZ 8192
#define D_SZ 1024
#define H_SZ 1024
#define K_SZ 2048   // D + H
#define N4H  4096   // 4*H

typedef __attribute__((ext_vector_type(4))) float f32x4;
typedef _Float16 f16;
typedef __attribute__((ext_vector_type(8))) f16 f16x8;
typedef unsigned short u16;
typedef __attribute__((ext_vector_type(4))) unsigned short u16x4;

static __device__ __forceinline__ u16 f2h(float f) {
    f16 h = (f16)f;
    return __builtin_bit_cast(unsigned short, h);
}

static __device__ __forceinline__ void load_lds16(const void* g, void* l) {
    __builtin_amdgcn_global_load_lds(
        (const __attribute__((address_space(1))) void*)g,
        (__attribute__((address_space(3))) void*)l, 16, 0, 0);
}

// ---------------------------------------------------------------------------
// Pack A[B][K] = [x | h_prev] as fp16
// ---------------------------------------------------------------------------
__global__ void convert_A(const float* __restrict__ x, const float* __restrict__ h,
                          u16* __restrict__ A) {
    const size_t nvec = (size_t)B_SZ * K_SZ / 4;
    const size_t stride = (size_t)gridDim.x * blockDim.x;
    for (size_t v = (size_t)blockIdx.x * blockDim.x + threadIdx.x; v < nvec; v += stride) {
        size_t e = v * 4;
        size_t row = e >> 11;
        int col = (int)(e & 2047);
        const float* src = (col < D_SZ) ? (x + row * D_SZ + col)
                                        : (h + row * H_SZ + (col - D_SZ));
        f32x4 val = *(const f32x4*)src;
        u16x4 o;
        o[0] = f2h(val[0]); o[1] = f2h(val[1]); o[2] = f2h(val[2]); o[3] = f2h(val[3]);
        *(u16x4*)(A + e) = o;
    }
}

// ---------------------------------------------------------------------------
// Pack W[4H][K]: row g*H+j = [Wg[j,:] | Rg[j,:]] as fp16, gate order i,f,o,z
// ---------------------------------------------------------------------------
__global__ void convert_W(const float* __restrict__ Wi, const float* __restrict__ Wf,
                          const float* __restrict__ Wo, const float* __restrict__ Wz,
                          const float* __restrict__ Ri, const float* __restrict__ Rf,
                          const float* __restrict__ Ro, const float* __restrict__ Rz,
                          u16* __restrict__ Wb) {
    const size_t nvec = (size_t)N4H * K_SZ / 4;
    const size_t stride = (size_t)gridDim.x * blockDim.x;
    for (size_t v = (size_t)blockIdx.x * blockDim.x + threadIdx.x; v < nvec; v += stride) {
        size_t e = v * 4;
        size_t n = e >> 11;
        int col = (int)(e & 2047);
        int g = (int)(n >> 10);
        int j = (int)(n & 1023);
        const float* Wg = (g == 0) ? Wi : (g == 1) ? Wf : (g == 2) ? Wo : Wz;
        const float* Rg = (g == 0) ? Ri : (g == 1) ? Rf : (g == 2) ? Ro : Rz;
        const float* src = (col < D_SZ) ? (Wg + (size_t)j * D_SZ + col)
                                        : (Rg + (size_t)j * H_SZ + (col - D_SZ));
        f32x4 val = *(const f32x4*)src;
        u16x4 o;
        o[0] = f2h(val[0]); o[1] = f2h(val[1]); o[2] = f2h(val[2]); o[3] = f2h(val[3]);
        *(u16x4*)(Wb + e) = o;
    }
}

// ---------------------------------------------------------------------------
// GEMM: pre[B][4H] = A[B][K] * W[4H][K]^T  (fp16 in, f32 out)
// 128x128 tile, BK=64, 4 waves (2x2), each wave 64x64 = 4x4 frags of 16x16x32.
// global_load_lds width 16 with pre-swizzled source (XOR seg^(row&7)), swizzled
// ds_read_b128 on the consume side (rule 21: linear dest + inv-swz src + swz read).
// ---------------------------------------------------------------------------
__global__ __launch_bounds__(256, 2)
void gemm_pre(const u16* __restrict__ A, const u16* __restrict__ W,
              float* __restrict__ pre) {
    __shared__ u16 lA[128 * 64];   // 16 KB
    __shared__ u16 lB[128 * 64];   // 16 KB

    const int tid = threadIdx.x;
    const int w  = tid >> 6;       // wave 0..3
    const int l  = tid & 63;       // lane
    const int wm = w >> 1;         // wave row (2)
    const int wn = w & 1;          // wave col (2)
    const int m0 = blockIdx.x * 128;
    const int n0 = blockIdx.y * 128;

    const int lrow8 = l >> 3;            // row within the wave's 8-row stripe
    const int lseg  = (l & 7) ^ lrow8;   // pre-swizzled global 16B-segment index

    const int fr = l & 15;   // fragment row (M for A, N for B), also C col
    const int kq = l >> 4;   // k-quad 0..3

    f32x4 acc[4][4] = {};

    for (int kt = 0; kt < K_SZ; kt += 64) {
        // ---- stage: 4 rounds x (A,B); each wave moves 1KB per call -------
#pragma unroll
        for (int r = 0; r < 4; ++r) {
            int rowA = r * 32 + w * 8 + lrow8;               // 0..127
            const u16* gA = A + (size_t)(m0 + rowA) * K_SZ + kt + lseg * 8;
            load_lds16(gA, (char*)lA + (r * 32 + w * 8) * 128);
            const u16* gB = W + (size_t)(n0 + rowA) * K_SZ + kt + lseg * 8;
            load_lds16(gB, (char*)lB + (r * 32 + w * 8) * 128);
        }
        __syncthreads();   // compiler emits vmcnt(0) drain before barrier

        // ---- compute: 2 k-slices of 32, 4x4 frags ------------------------
#pragma unroll
        for (int ks = 0; ks < 2; ++ks) {
            f16x8 af[4], bfr[4];
#pragma unroll
            for (int mi = 0; mi < 4; ++mi) {
                int row = wm * 64 + mi * 16 + fr;
                int seg = (ks * 4 + kq) ^ (row & 7);
                af[mi] = *(const f16x8*)&lA[row * 64 + seg * 8];
            }
#pragma unroll
            for (int ni = 0; ni < 4; ++ni) {
                int row = wn * 64 + ni * 16 + fr;
                int seg = (ks * 4 + kq) ^ (row & 7);
                bfr[ni] = *(const f16x8*)&lB[row * 64 + seg * 8];
            }
#pragma unroll
            for (int mi = 0; mi < 4; ++mi)
#pragma unroll
                for (int ni = 0; ni < 4; ++ni)
                    acc[mi][ni] = __builtin_amdgcn_mfma_f32_16x16x32_f16(
                        af[mi], bfr[ni], acc[mi][ni], 0, 0, 0);
        }
        __syncthreads();   // protect LDS before next stage overwrites
    }

    // ---- write pre (f32). C/D: col = lane&15, row = (lane>>4)*4 + reg ----
#pragma unroll
    for (int mi = 0; mi < 4; ++mi) {
#pragma unroll
        for (int ni = 0; ni < 4; ++ni) {
            int col = n0 + wn * 64 + ni * 16 + fr;
            int rbase = m0 + wm * 64 + mi * 16 + kq * 4;
#pragma unroll
            for (int r2 = 0; r2 < 4; ++r2) {
                pre[(size_t)(rbase + r2) * N4H + col] = acc[mi][ni][r2];
            }
        }
    }
}

// ---------------------------------------------------------------------------
// Elementwise epilogue + output assembly
// ---------------------------------------------------------------------------
__global__ void epilogue_k(const float* __restrict__ pre,
                           const float* __restrict__ c_prev, const float* __restrict__ C_prev,
                           const float* __restrict__ n_prev, const float* __restrict__ m_prev,
                           const float* __restrict__ bi, const float* __restrict__ bfv,
                           const float* __restrict__ bo, const float* __restrict__ bz,
                           float* __restrict__ out) {
    const size_t BH = (size_t)B_SZ * H_SZ;
    const size_t nvec = BH / 4;
    const size_t stride = (size_t)gridDim.x * blockDim.x;
    for (size_t v = (size_t)blockIdx.x * blockDim.x + threadIdx.x; v < nvec; v += stride) {
        size_t e = v * 4;
        size_t b = e >> 10;
        int j = (int)(e & 1023);
        const size_t prow = b * N4H;
        f32x4 pi4 = *(const f32x4*)&pre[prow + j]             + *(const f32x4*)&bi[j];
        f32x4 pf4 = *(const f32x4*)&pre[prow + H_SZ + j]      + *(const f32x4*)&bfv[j];
        f32x4 po4 = *(const f32x4*)&pre[prow + 2 * H_SZ + j]  + *(const f32x4*)&bo[j];
        f32x4 pz4 = *(const f32x4*)&pre[prow + 3 * H_SZ + j]  + *(const f32x4*)&bz[j];
        f32x4 cp = *(const f32x4*)&c_prev[e];
        f32x4 Cp = *(const f32x4*)&C_prev[e];
        f32x4 np = *(const f32x4*)&n_prev[e];
        f32x4 mp = *(const f32x4*)&m_prev[e];
        f32x4 ho, co, no, mo;
#pragma unroll
        for (int q = 0; q < 4; ++q) {
            float pi = pi4[q], pf = pf4[q], po = po4[q], pz = pz4[q];
            float iv = __expf(pi);
            float fv = 1.0f / (1.0f + __expf(-pf));
            float ov = 1.0f / (1.0f + __expf(-po));
            float e2 = __expf(2.0f * pz);
            float zv = 1.0f - 2.0f / (e2 + 1.0f);   // tanh(pz)
            float cv = fv * cp[q] + iv * zv;
            float nv = fv * np[q] + iv;
            float mv = fmaxf(__logf(fv) + mp[q], pi);
            float hv = ov * (cv / nv);
            ho[q] = hv; co[q] = cv; no[q] = nv; mo[q] = mv;
        }
        *(f32x4*)&out[e]           = ho;
        *(f32x4*)&out[BH + e]      = co;
        *(f32x4*)&out[2 * BH + e]  = Cp;
        *(f32x4*)&out[3 * BH + e]  = no;
        *(f32x4*)&out[4 * BH + e]  = mo;
    }
}

// ---------------------------------------------------------------------------
extern "C" void kernel_launch(void* const* d_in, const int* in_sizes, int n_in,
                              void* d_out, int out_size, void* d_ws, size_t ws_size,
                              hipStream_t stream) {
    // setup_inputs() dict order:
    const float* x      = (const float*)d_in[0];
    const float* h_prev = (const float*)d_in[1];
    const float* c_prev = (const float*)d_in[2];
    const float* C_prev = (const float*)d_in[3];
    const float* n_prev = (const float*)d_in[4];
    const float* m_prev = (const float*)d_in[5];
    const float* Wz = (const float*)d_in[6];
    const float* bz = (const float*)d_in[7];
    const float* Rz = (const float*)d_in[8];
    const float* Wi = (const float*)d_in[9];
    const float* bi = (const float*)d_in[10];
    const float* Ri = (const float*)d_in[11];
    const float* Wf = (const float*)d_in[12];
    const float* bf = (const float*)d_in[13];
    const float* Rf = (const float*)d_in[14];
    const float* Wo = (const float*)d_in[15];
    const float* bo = (const float*)d_in[16];
    const float* Ro = (const float*)d_in[17];
    float* out = (float*)d_out;

    // workspace layout: A_f16 (32MB) | W_f16 (16MB) | pre_f32 (128MB)
    u16* Abuf = (u16*)d_ws;
    u16* Wbuf = (u16*)((char*)d_ws + (size_t)32 * 1024 * 1024);
    float* pre = (float*)((char*)d_ws + (size_t)48 * 1024 * 1024);

    convert_A<<<2048, 256, 0, stream>>>(x, h_prev, Abuf);
    convert_W<<<2048, 256, 0, stream>>>(Wi, Wf, Wo, Wz, Ri, Rf, Ro, Rz, Wbuf);
    gemm_pre<<<dim3(B_SZ / 128, N4H / 128), 256, 0, stream>>>(Abuf, Wbuf, pre);
    epilogue_k<<<2048, 256, 0, stream>>>(pre, c_prev, C_prev, n_prev, m_prev,
                                         bi, bf, bo, bz, out);
}

// Round 2
// 225.813 us; speedup vs baseline: 1.0910x; 1.0910x over previous
//
#include <hip/hip_runtime.h>

// ---------------------------------------------------------------------------
// sLSTM cell, B=8192, D=1024, H=1024.
//   pre[B,4H] = [x,h_prev] @ [Wg|Rg]^T  (K = D+H = 2048)
//   i=exp(pi+bi), f=sig(pf+bf), o=sig(po+bo), z=tanh(pz+bz)
//   c=f*c_prev+i*z ; n=f*n_prev+i ; m=max(log f + m_prev, pi) ; h=o*c/n
//   outputs (flat): h, c, C_prev(copy), n, m  -- each B*H f32
//
// Round 2: epilogue fused into the GEMM. W is packed GATE-INTERLEAVED at
// 16-row granularity: packed row r -> gate (r>>4)&3, j=(r>>6)*16+(r&15).
// A wave's 4 N-fragments (ni=0..3) are then {pi,pf,po,pz} of the SAME j
// (j = ((n0+wn*64)>>6)*16 + (lane&15)), so the sLSTM epilogue is fully
// lane-local. C_prev passthrough via hipMemcpyAsync D2D.
// ---------------------------------------------------------------------------

#define B_SZ 8192
#define D_SZ 1024
#define H_SZ 1024
#define K_SZ 2048   // D + H
#define N4H  4096   // 4*H

typedef __attribute__((ext_vector_type(4))) float f32x4;
typedef _Float16 f16;
typedef __attribute__((ext_vector_type(8))) f16 f16x8;
typedef unsigned short u16;
typedef __attribute__((ext_vector_type(4))) unsigned short u16x4;

static __device__ __forceinline__ u16 f2h(float f) {
    f16 h = (f16)f;
    return __builtin_bit_cast(unsigned short, h);
}

static __device__ __forceinline__ void load_lds16(const void* g, void* l) {
    __builtin_amdgcn_global_load_lds(
        (const __attribute__((address_space(1))) void*)g,
        (__attribute__((address_space(3))) void*)l, 16, 0, 0);
}

// ---------------------------------------------------------------------------
// Pack A[B][K] = [x | h_prev] as fp16
// ---------------------------------------------------------------------------
__global__ void convert_A(const float* __restrict__ x, const float* __restrict__ h,
                          u16* __restrict__ A) {
    const size_t nvec = (size_t)B_SZ * K_SZ / 4;
    const size_t stride = (size_t)gridDim.x * blockDim.x;
    for (size_t v = (size_t)blockIdx.x * blockDim.x + threadIdx.x; v < nvec; v += stride) {
        size_t e = v * 4;
        size_t row = e >> 11;
        int col = (int)(e & 2047);
        const float* src = (col < D_SZ) ? (x + row * D_SZ + col)
                                        : (h + row * H_SZ + (col - D_SZ));
        f32x4 val = *(const f32x4*)src;
        u16x4 o;
        o[0] = f2h(val[0]); o[1] = f2h(val[1]); o[2] = f2h(val[2]); o[3] = f2h(val[3]);
        *(u16x4*)(A + e) = o;
    }
}

// ---------------------------------------------------------------------------
// Pack W[4H][K] gate-interleaved: packed row r -> gate g=(r>>4)&3,
// j = (r>>6)*16 + (r&15); content = [Wg[j,:] | Rg[j,:]] as fp16.
// Gate order g: 0=i, 1=f, 2=o, 3=z.
// ---------------------------------------------------------------------------
__global__ void convert_W(const float* __restrict__ Wi, const float* __restrict__ Wf,
                          const float* __restrict__ Wo, const float* __restrict__ Wz,
                          const float* __restrict__ Ri, const float* __restrict__ Rf,
                          const float* __restrict__ Ro, const float* __restrict__ Rz,
                          u16* __restrict__ Wb) {
    const size_t nvec = (size_t)N4H * K_SZ / 4;
    const size_t stride = (size_t)gridDim.x * blockDim.x;
    for (size_t v = (size_t)blockIdx.x * blockDim.x + threadIdx.x; v < nvec; v += stride) {
        size_t e = v * 4;
        size_t r = e >> 11;                 // packed row 0..4095
        int col = (int)(e & 2047);
        int g = (int)(r >> 4) & 3;          // gate
        int j = (int)((r >> 6) << 4) | (int)(r & 15);
        const float* Wg = (g == 0) ? Wi : (g == 1) ? Wf : (g == 2) ? Wo : Wz;
        const float* Rg = (g == 0) ? Ri : (g == 1) ? Rf : (g == 2) ? Ro : Rz;
        const float* src = (col < D_SZ) ? (Wg + (size_t)j * D_SZ + col)
                                        : (Rg + (size_t)j * H_SZ + (col - D_SZ));
        f32x4 val = *(const f32x4*)src;
        u16x4 o;
        o[0] = f2h(val[0]); o[1] = f2h(val[1]); o[2] = f2h(val[2]); o[3] = f2h(val[3]);
        *(u16x4*)(Wb + e) = o;
    }
}

// ---------------------------------------------------------------------------
// Fused GEMM + sLSTM epilogue.
// 128x128 tile, BK=64, 4 waves (2x2), each wave 64x64 = 4x4 frags of 16x16x32.
// global_load_lds width 16 with pre-swizzled source (XOR seg^(row&7)), swizzled
// ds_read_b128 on the consume side.
// After the K-loop: acc[mi][0..3] = {pi,pf,po,pz} for j = jblk*16+fr,
// rows m0+wm*64+mi*16+kq*4+r2 -> compute h,c,n,m in-lane and store.
// ---------------------------------------------------------------------------
__global__ __launch_bounds__(256, 2)
void gemm_fused(const u16* __restrict__ A, const u16* __restrict__ W,
                const float* __restrict__ c_prev, const float* __restrict__ n_prev,
                const float* __restrict__ m_prev,
                const float* __restrict__ bi, const float* __restrict__ bfv,
                const float* __restrict__ bo, const float* __restrict__ bz,
                float* __restrict__ out) {
    __shared__ u16 lA[128 * 64];   // 16 KB
    __shared__ u16 lB[128 * 64];   // 16 KB

    const int tid = threadIdx.x;
    const int w  = tid >> 6;       // wave 0..3
    const int l  = tid & 63;       // lane
    const int wm = w >> 1;         // wave row (2)
    const int wn = w & 1;          // wave col (2)
    const int m0 = blockIdx.x * 128;
    const int n0 = blockIdx.y * 128;

    const int lrow8 = l >> 3;            // row within the wave's 8-row stripe
    const int lseg  = (l & 7) ^ lrow8;   // pre-swizzled global 16B-segment index

    const int fr = l & 15;   // fragment row (M for A, N for B), also C col
    const int kq = l >> 4;   // k-quad 0..3

    f32x4 acc[4][4] = {};

    for (int kt = 0; kt < K_SZ; kt += 64) {
        // ---- stage: 4 rounds x (A,B); each wave moves 1KB per call -------
#pragma unroll
        for (int r = 0; r < 4; ++r) {
            int rowA = r * 32 + w * 8 + lrow8;               // 0..127
            const u16* gA = A + (size_t)(m0 + rowA) * K_SZ + kt + lseg * 8;
            load_lds16(gA, (char*)lA + (r * 32 + w * 8) * 128);
            const u16* gB = W + (size_t)(n0 + rowA) * K_SZ + kt + lseg * 8;
            load_lds16(gB, (char*)lB + (r * 32 + w * 8) * 128);
        }
        __syncthreads();

        // ---- compute: 2 k-slices of 32, 4x4 frags ------------------------
#pragma unroll
        for (int ks = 0; ks < 2; ++ks) {
            f16x8 af[4], bfr[4];
#pragma unroll
            for (int mi = 0; mi < 4; ++mi) {
                int row = wm * 64 + mi * 16 + fr;
                int seg = (ks * 4 + kq) ^ (row & 7);
                af[mi] = *(const f16x8*)&lA[row * 64 + seg * 8];
            }
#pragma unroll
            for (int ni = 0; ni < 4; ++ni) {
                int row = wn * 64 + ni * 16 + fr;
                int seg = (ks * 4 + kq) ^ (row & 7);
                bfr[ni] = *(const f16x8*)&lB[row * 64 + seg * 8];
            }
#pragma unroll
            for (int mi = 0; mi < 4; ++mi)
#pragma unroll
                for (int ni = 0; ni < 4; ++ni)
                    acc[mi][ni] = __builtin_amdgcn_mfma_f32_16x16x32_f16(
                        af[mi], bfr[ni], acc[mi][ni], 0, 0, 0);
        }
        __syncthreads();
    }

    // ---- fused sLSTM epilogue (fully lane-local) -------------------------
    const size_t BH = (size_t)B_SZ * H_SZ;
    const int j = ((n0 + wn * 64) >> 6) * 16 + fr;    // 0..1023
    const float bvi = bi[j], bvf = bfv[j], bvo = bo[j], bvz = bz[j];

#pragma unroll
    for (int mi = 0; mi < 4; ++mi) {
        const int rbase = m0 + wm * 64 + mi * 16 + kq * 4;
#pragma unroll
        for (int r2 = 0; r2 < 4; ++r2) {
            const size_t idx = (size_t)(rbase + r2) * H_SZ + j;
            float pi = acc[mi][0][r2] + bvi;
            float pf = acc[mi][1][r2] + bvf;
            float po = acc[mi][2][r2] + bvo;
            float pz = acc[mi][3][r2] + bvz;
            float iv = __expf(pi);
            float fv = 1.0f / (1.0f + __expf(-pf));
            float ov = 1.0f / (1.0f + __expf(-po));
            float e2 = __expf(2.0f * pz);
            float zv = 1.0f - 2.0f / (e2 + 1.0f);     // tanh(pz)
            float cv = fv * c_prev[idx] + iv * zv;
            float nv = fv * n_prev[idx] + iv;
            float mv = fmaxf(__logf(fv) + m_prev[idx], pi);
            out[idx]          = ov * (cv / nv);       // h
            out[BH + idx]     = cv;                   // c
            out[3 * BH + idx] = nv;                   // n
            out[4 * BH + idx] = mv;                   // m
        }
    }
}

// ---------------------------------------------------------------------------
extern "C" void kernel_launch(void* const* d_in, const int* in_sizes, int n_in,
                              void* d_out, int out_size, void* d_ws, size_t ws_size,
                              hipStream_t stream) {
    // setup_inputs() dict order:
    const float* x      = (const float*)d_in[0];
    const float* h_prev = (const float*)d_in[1];
    const float* c_prev = (const float*)d_in[2];
    const float* C_prev = (const float*)d_in[3];
    const float* n_prev = (const float*)d_in[4];
    const float* m_prev = (const float*)d_in[5];
    const float* Wz = (const float*)d_in[6];
    const float* bz = (const float*)d_in[7];
    const float* Rz = (const float*)d_in[8];
    const float* Wi = (const float*)d_in[9];
    const float* bi = (const float*)d_in[10];
    const float* Ri = (const float*)d_in[11];
    const float* Wf = (const float*)d_in[12];
    const float* bf = (const float*)d_in[13];
    const float* Rf = (const float*)d_in[14];
    const float* Wo = (const float*)d_in[15];
    const float* bo = (const float*)d_in[16];
    const float* Ro = (const float*)d_in[17];
    float* out = (float*)d_out;

    const size_t BH = (size_t)B_SZ * H_SZ;

    // workspace layout: A_f16 (32MB) | W_f16 (16MB)
    u16* Abuf = (u16*)d_ws;
    u16* Wbuf = (u16*)((char*)d_ws + (size_t)32 * 1024 * 1024);

    convert_A<<<2048, 256, 0, stream>>>(x, h_prev, Abuf);
    convert_W<<<2048, 256, 0, stream>>>(Wi, Wf, Wo, Wz, Ri, Rf, Ro, Rz, Wbuf);

    // C_prev passthrough (output slot 2)
    hipMemcpyAsync(out + 2 * BH, C_prev, BH * sizeof(float),
                   hipMemcpyDeviceToDevice, stream);

    gemm_fused<<<dim3(B_SZ / 128, N4H / 128), 256, 0, stream>>>(
        Abuf, Wbuf, c_prev, n_prev, m_prev, bi, bf, bo, bz, out);
}